// Round 6
// baseline (317.563 us; speedup 1.0000x reference)
//
#include <hip/hip_runtime.h>

#define NF 64        // feature width
#define BD 128       // dst chunks (rows of the Gin count matrix)
#define BS 16        // src chunks (deg_out path)
#define NWMAX 12544  // packed-byte LDS counters: supports n <= 50176

// f32 -> bf16 round-to-nearest-even
__device__ __forceinline__ unsigned short f2bf(float f) {
  unsigned int u = __float_as_uint(f);
  return (unsigned short)((u + 0x7fffu + ((u >> 16) & 1u)) >> 16);
}

// ---------------------------------------------------------------------------
// Histograms with packed 8-bit LDS counters (4 per int). Blocks [0,BD):
// dst-chunk b -> Gin[b][n] (uchar counts, vectorized word store). Blocks
// [BD,BD+BS): src-chunk -> coalesced atomicAdd into deg_out (pre-zeroed).
// Counts per (chunk,node) are tiny (Poisson << 255) -> bytes never overflow.
__global__ __launch_bounds__(256) void hist_kernel(
    const int* __restrict__ src, const int* __restrict__ dst,
    unsigned char* __restrict__ Gin, int* __restrict__ deg_out,
    int n, int gs, int nE) {
  __shared__ int cnt[NWMAX];
  const int t = threadIdx.x;
  const int nw = (n + 3) >> 2;
  for (int i = t; i < nw; i += 256) cnt[i] = 0;
  __syncthreads();
  if ((int)blockIdx.x < BD) {
    const int b = blockIdx.x;
    const int chunk = (nE + BD - 1) / BD;
    const int lo = b * chunk, hi = min(lo + chunk, nE);
    for (int e = lo + t; e < hi; e += 256) {
      int d = dst[e];
      atomicAdd(&cnt[d >> 2], 1u << ((d & 3) * 8));
    }
    __syncthreads();
    unsigned int* G = (unsigned int*)(Gin + (size_t)b * gs);
    for (int w = t; w < nw; w += 256) G[w] = (unsigned int)cnt[w];
  } else {
    const int b = blockIdx.x - BD;
    const int chunk = (nE + BS - 1) / BS;
    const int lo = b * chunk, hi = min(lo + chunk, nE);
    for (int e = lo + t; e < hi; e += 256) {
      int s = src[e];
      atomicAdd(&cnt[s >> 2], 1u << ((s & 3) * 8));
    }
    __syncthreads();
    for (int i = t; i < n; i += 256) {
      int c = (cnt[i >> 2] >> ((i & 3) * 8)) & 0xff;
      if (c) atomicAdd(&deg_out[i], c);  // coalesced address pattern
    }
  }
}

// Per 4-node word: exclusive scan of Gin down the BD chunks (packed-byte add,
// carry-free since bases <= max in-degree ~45), in place; totals -> deg_in.
__global__ __launch_bounds__(64) void colscan_kernel(
    unsigned char* __restrict__ Gin, int* __restrict__ deg_in, int n, int gs) {
  int w = blockIdx.x * 64 + threadIdx.x;  // word index = 4 nodes
  int n0 = w * 4;
  if (n0 >= n) return;
  unsigned int acc = 0;
  #pragma unroll 8
  for (int b = 0; b < BD; ++b) {
    unsigned int* p = (unsigned int*)(Gin + (size_t)b * gs) + w;
    unsigned int c = *p;
    *p = acc;
    acc += c;  // packed byte add, no cross-byte carries
  }
  if (n0 + 3 < n) {
    int4 d;
    d.x = acc & 0xff; d.y = (acc >> 8) & 0xff;
    d.z = (acc >> 16) & 0xff; d.w = (acc >> 24) & 0xff;
    *(int4*)&deg_in[n0] = d;
  } else {
    for (int k = 0; k < 4 && n0 + k < n; ++k)
      deg_in[n0 + k] = (acc >> (8 * k)) & 0xff;
  }
}

// ---------------------------------------------------------------------------
// Exclusive scan of deg_in -> row_start. scan1: per-block scan + block sums.
__global__ __launch_bounds__(256) void scan1_kernel(
    const int* __restrict__ deg, int* __restrict__ lscan,
    int* __restrict__ bsum, int n) {
  __shared__ int s[256];
  int tid = threadIdx.x;
  int i = blockIdx.x * 256 + tid;
  int v = (i < n) ? deg[i] : 0;
  s[tid] = v;
  __syncthreads();
  #pragma unroll
  for (int off = 1; off < 256; off <<= 1) {
    int t2 = (tid >= off) ? s[tid - off] : 0;
    __syncthreads();
    s[tid] += t2;
    __syncthreads();
  }
  if (i < n) lscan[i] = s[tid] - v;
  if (tid == 255) bsum[blockIdx.x] = s[255];
}

// scan3: block b reduces bsum[0..b) itself (NB<=256), finalizes row_start and
// deg^{-1/2} factors.
__global__ __launch_bounds__(256) void scan3_kernel(
    const int* __restrict__ lscan, const int* __restrict__ bsum,
    const int* __restrict__ deg_out, const int* __restrict__ deg_in,
    int* __restrict__ row_start, float* __restrict__ so, float* __restrict__ si,
    int n, int nE) {
  __shared__ int red[256];
  const int tid = threadIdx.x;
  const int b = blockIdx.x;
  red[tid] = (tid < b) ? bsum[tid] : 0;
  __syncthreads();
  #pragma unroll
  for (int s = 128; s > 0; s >>= 1) {
    if (tid < s) red[tid] += red[tid + s];
    __syncthreads();
  }
  const int off = red[0];
  const int i = b * 256 + tid;
  if (b == 0 && tid == 0) row_start[n] = nE;
  if (i < n) {
    row_start[i] = lscan[i] + off;
    int dO = deg_out[i];
    int dI = deg_in[i];
    so[i] = dO > 0 ? rsqrtf((float)dO) : 0.f;
    si[i] = dI > 0 ? rsqrtf((float)dI) : 0.f;
  }
}

// Atomic-free placement: block b rebuilds chunk-b local ranks in packed-byte
// LDS; pos = row_start[d] + Gin[b][d] + rank. Single pass over dst; only
// scattered writes are the 800K ushort stores.
__global__ __launch_bounds__(256) void place_kernel(
    const int* __restrict__ src, const int* __restrict__ dst,
    const unsigned char* __restrict__ Gin, const int* __restrict__ row_start,
    unsigned short* __restrict__ sorted, int n, int gs, int nE) {
  __shared__ int cnt[NWMAX];
  const int t = threadIdx.x;
  const int nw = (n + 3) >> 2;
  for (int i = t; i < nw; i += 256) cnt[i] = 0;
  __syncthreads();
  const int b = blockIdx.x;
  const int chunk = (nE + BD - 1) / BD;
  const int lo = b * chunk, hi = min(lo + chunk, nE);
  for (int e = lo + t; e < hi; e += 256) {
    int d = dst[e];
    int sh = (d & 3) * 8;
    unsigned int old = atomicAdd(&cnt[d >> 2], 1u << sh);
    int rank = (int)((old >> sh) & 0xffu);
    int pos = row_start[d] + (int)Gin[(size_t)b * gs + d] + rank;
    sorted[pos] = (unsigned short)src[e];
  }
}

// ---------------------------------------------------------------------------
// Register-blocked GEMM (layer 1): h1 = bf16((x*so) @ W1).
__global__ __launch_bounds__(256) void gemm1_kernel(
    const float* __restrict__ A, const float* __restrict__ so,
    const float* __restrict__ W, unsigned short* __restrict__ H, int n) {
  __shared__ float Wl[NF * NF];
  __shared__ float Xl[NF * 68];
  const int t = threadIdx.x;

  #pragma unroll
  for (int i = 0; i < 16; ++i) Wl[t + 256 * i] = W[t + 256 * i];

  const int row0 = blockIdx.x * 64;
  #pragma unroll
  for (int i = 0; i < 16; ++i) {
    int idx = t + 256 * i;
    int r = idx >> 6;
    int c = idx & 63;
    int gr = row0 + r;
    float v = 0.f;
    if (gr < n) v = A[(size_t)gr * NF + c] * so[gr];
    Xl[r * 68 + c] = v;
  }
  __syncthreads();

  const int tx = t & 15;
  const int ty = t >> 4;
  float4 acc0 = {0, 0, 0, 0}, acc1 = {0, 0, 0, 0};
  float4 acc2 = {0, 0, 0, 0}, acc3 = {0, 0, 0, 0};

  #pragma unroll
  for (int k4 = 0; k4 < 16; ++k4) {
    const float4 a0 = *(const float4*)&Xl[(ty * 4 + 0) * 68 + k4 * 4];
    const float4 a1 = *(const float4*)&Xl[(ty * 4 + 1) * 68 + k4 * 4];
    const float4 a2 = *(const float4*)&Xl[(ty * 4 + 2) * 68 + k4 * 4];
    const float4 a3 = *(const float4*)&Xl[(ty * 4 + 3) * 68 + k4 * 4];
    const float4 b0 = *(const float4*)&Wl[(k4 * 4 + 0) * NF + tx * 4];
    const float4 b1 = *(const float4*)&Wl[(k4 * 4 + 1) * NF + tx * 4];
    const float4 b2 = *(const float4*)&Wl[(k4 * 4 + 2) * NF + tx * 4];
    const float4 b3 = *(const float4*)&Wl[(k4 * 4 + 3) * NF + tx * 4];

#define FMA4(ACC, AV, BV)                         \
    ACC.x = fmaf(AV, BV.x, ACC.x);                \
    ACC.y = fmaf(AV, BV.y, ACC.y);                \
    ACC.z = fmaf(AV, BV.z, ACC.z);                \
    ACC.w = fmaf(AV, BV.w, ACC.w);
    FMA4(acc0, a0.x, b0) FMA4(acc0, a0.y, b1) FMA4(acc0, a0.z, b2) FMA4(acc0, a0.w, b3)
    FMA4(acc1, a1.x, b0) FMA4(acc1, a1.y, b1) FMA4(acc1, a1.z, b2) FMA4(acc1, a1.w, b3)
    FMA4(acc2, a2.x, b0) FMA4(acc2, a2.y, b1) FMA4(acc2, a2.z, b2) FMA4(acc2, a2.w, b3)
    FMA4(acc3, a3.x, b0) FMA4(acc3, a3.y, b1) FMA4(acc3, a3.z, b2) FMA4(acc3, a3.w, b3)
#undef FMA4
  }

  const int col = tx * 4;
  #pragma unroll
  for (int i = 0; i < 4; ++i) {
    int gr = row0 + ty * 4 + i;
    if (gr >= n) continue;
    float4 v = (i == 0) ? acc0 : (i == 1) ? acc1 : (i == 2) ? acc2 : acc3;
    ushort4 o;
    o.x = f2bf(v.x); o.y = f2bf(v.y); o.z = f2bf(v.z); o.w = f2bf(v.w);
    *(ushort4*)&H[(size_t)gr * NF + col] = o;
  }
}

// ---------------------------------------------------------------------------
// Shared gather/accumulate: one wave per node over bf16 rows (128 B). Lane
// group g=lane>>3 handles row srcs[e+g]; lane loads float4 = 8 bf16 -> one
// instruction gathers 8 rows. Butterfly xor 8/16/32 leaves the FULL row sum
// in every lane (features (lane&7)*8 .. +7 in acc[0..7]).
__device__ __forceinline__ void gather_sum(
    const unsigned short* __restrict__ H, const unsigned short* __restrict__ srcs,
    int beg, int end, int g, int c, float* acc) {
  const float4* Hv = (const float4*)H;
  int e = beg;
  for (; e + 16 <= end; e += 16) {
    int ia = srcs[e + g];
    int ib = srcs[e + 8 + g];
    float4 va = Hv[(size_t)ia * 8 + c];
    float4 vb = Hv[(size_t)ib * 8 + c];
    const unsigned int* pa = (const unsigned int*)&va;
    const unsigned int* pb = (const unsigned int*)&vb;
    #pragma unroll
    for (int k = 0; k < 4; ++k) {
      acc[2 * k]     += __uint_as_float(pa[k] << 16) + __uint_as_float(pb[k] << 16);
      acc[2 * k + 1] += __uint_as_float(pa[k] & 0xffff0000u) + __uint_as_float(pb[k] & 0xffff0000u);
    }
  }
  if (e + 8 <= end) {
    int ia = srcs[e + g];
    float4 va = Hv[(size_t)ia * 8 + c];
    const unsigned int* pa = (const unsigned int*)&va;
    #pragma unroll
    for (int k = 0; k < 4; ++k) {
      acc[2 * k]     += __uint_as_float(pa[k] << 16);
      acc[2 * k + 1] += __uint_as_float(pa[k] & 0xffff0000u);
    }
    e += 8;
  }
  if (e < end) {
    int idx = (e + g < end) ? (e + g) : (end - 1);
    float m = (e + g < end) ? 1.f : 0.f;
    int ia = srcs[idx];
    float4 va = Hv[(size_t)ia * 8 + c];
    const unsigned int* pa = (const unsigned int*)&va;
    #pragma unroll
    for (int k = 0; k < 4; ++k) {
      acc[2 * k]     += m * __uint_as_float(pa[k] << 16);
      acc[2 * k + 1] += m * __uint_as_float(pa[k] & 0xffff0000u);
    }
  }
  #pragma unroll
  for (int d = 8; d <= 32; d <<= 1) {
    #pragma unroll
    for (int k = 0; k < 8; ++k) acc[k] += __shfl_xor(acc[k], d);
  }
}

// Fused agg0 + layer-2 GEMM: t = relu(segsum(h1)*si + b1) * so applied
// in-register, then per-node matvec h2[node][j] = sum_k t[k]*W2[k][j] via
// 64-step shfl broadcast + LDS W2. Deletes the tbuf round-trip entirely.
__global__ __launch_bounds__(256) void agg_gemm2_kernel(
    const unsigned short* __restrict__ H1, const int* __restrict__ row_start,
    const unsigned short* __restrict__ srcs, const float* __restrict__ si,
    const float* __restrict__ so, const float* __restrict__ b1,
    const float* __restrict__ W2, unsigned short* __restrict__ H2, int n) {
  __shared__ float Wl[NF * NF];
  const int t = threadIdx.x;
  #pragma unroll
  for (int i = 0; i < 16; ++i) Wl[t + 256 * i] = W2[t + 256 * i];
  __syncthreads();

  int node = blockIdx.x * 4 + (t >> 6);
  if (node >= n) return;
  const int lane = t & 63;
  const int g = lane >> 3;
  const int c = lane & 7;

  float acc[8] = {0, 0, 0, 0, 0, 0, 0, 0};
  gather_sum(H1, srcs, row_start[node], row_start[node + 1], g, c, acc);

  // epilogue on this lane's 8 features (c*8 .. c*8+7)
  const float sin = si[node];
  const float son = so[node];
  #pragma unroll
  for (int k = 0; k < 8; ++k)
    acc[k] = fmaxf(fmaf(acc[k], sin, b1[c * 8 + k]), 0.f) * son;

  // matvec: lane j computes h2[node][j]; t[k] lives in acc[k&7] of lane k>>3
  float o = 0.f;
  #pragma unroll
  for (int k = 0; k < NF; ++k) {
    float tk = __shfl(acc[k & 7], k >> 3);
    o = fmaf(tk, Wl[k * NF + lane], o);
  }
  H2[(size_t)node * NF + lane] = f2bf(o);
}

// Final aggregation: out = segsum(h2)*si + b2 (f32 output).
__global__ __launch_bounds__(256) void agg_final_kernel(
    const unsigned short* __restrict__ H2, const int* __restrict__ row_start,
    const unsigned short* __restrict__ srcs, const float* __restrict__ si,
    const float* __restrict__ b2, float* __restrict__ out, int n) {
  int node = blockIdx.x * 4 + (threadIdx.x >> 6);
  if (node >= n) return;
  const int lane = threadIdx.x & 63;
  const int g = lane >> 3;
  const int c = lane & 7;

  float acc[8] = {0, 0, 0, 0, 0, 0, 0, 0};
  gather_sum(H2, srcs, row_start[node], row_start[node + 1], g, c, acc);

  if (g == 0) {
    const float sin = si[node];
    const float4 b4a = *(const float4*)&b2[c * 8];
    const float4 b4b = *(const float4*)&b2[c * 8 + 4];
    const float bb[8] = {b4a.x, b4a.y, b4a.z, b4a.w, b4b.x, b4b.y, b4b.z, b4b.w};
    float r[8];
    #pragma unroll
    for (int k = 0; k < 8; ++k) r[k] = fmaf(acc[k], sin, bb[k]);
    *(float4*)&out[(size_t)node * NF + c * 8]     = make_float4(r[0], r[1], r[2], r[3]);
    *(float4*)&out[(size_t)node * NF + c * 8 + 4] = make_float4(r[4], r[5], r[6], r[7]);
  }
}

// ---------------------------------------------------------------------------
extern "C" void kernel_launch(void* const* d_in, const int* in_sizes, int n_in,
                              void* d_out, int out_size, void* d_ws, size_t ws_size,
                              hipStream_t stream) {
  const float* x  = (const float*)d_in[0];
  const float* W1 = (const float*)d_in[1];
  const float* b1 = (const float*)d_in[2];
  const float* W2 = (const float*)d_in[3];
  const float* b2 = (const float*)d_in[4];
  const int* src  = (const int*)d_in[5];
  const int* dst  = (const int*)d_in[6];
  float* out = (float*)d_out;

  const int N = in_sizes[0] / NF;   // 50000 (< 65536 for ushort ids, <= 50176 for LDS hist)
  const int E = in_sizes[5];        // 800000
  const int NB = (N + 255) / 256;   // 196 <= 256
  const int gs = (N + 3) & ~3;      // Gin row stride (word-aligned)

  // Workspace (~22 MB)
  char* ws = (char*)d_ws;
  size_t p = 0;
  auto alloc = [&](size_t bytes) -> void* {
    void* r = ws + p;
    p = (p + bytes + 255) & ~(size_t)255;
    return r;
  };
  int*   deg_out_i  = (int*)  alloc((size_t)N * 4);
  int*   deg_in_i   = (int*)  alloc((size_t)N * 4);
  float* so         = (float*)alloc((size_t)N * 4);
  float* si         = (float*)alloc((size_t)N * 4);
  int*   row_start  = (int*)  alloc((size_t)(N + 1) * 4);
  int*   bsum       = (int*)  alloc((size_t)NB * 4);
  int*   lscan      = (int*)  alloc((size_t)N * 4);
  unsigned short* sorted_u16 = (unsigned short*)alloc((size_t)E * 2);
  unsigned short* h1 = (unsigned short*)alloc((size_t)N * NF * 2);  // bf16
  unsigned short* h2 = (unsigned short*)alloc((size_t)N * NF * 2);  // bf16
  unsigned char* Gin = (unsigned char*)alloc((size_t)BD * gs);      // 6.4 MB

  // 1. histograms: Gin count matrix + deg_out (deg_out must be zeroed)
  hipMemsetAsync(deg_out_i, 0, (size_t)N * 4, stream);
  hist_kernel<<<BD + BS, 256, 0, stream>>>(src, dst, Gin, deg_out_i, N, gs, E);

  // 2. column scan -> per-chunk bases + deg_in
  colscan_kernel<<<(gs / 4 + 63) / 64, 64, 0, stream>>>(Gin, deg_in_i, N, gs);

  // 3. row_start + so/si
  scan1_kernel<<<NB, 256, 0, stream>>>(deg_in_i, lscan, bsum, N);
  scan3_kernel<<<NB, 256, 0, stream>>>(lscan, bsum, deg_out_i, deg_in_i,
                                       row_start, so, si, N, E);

  // 4. atomic-free placement (single pass over dst)
  place_kernel<<<BD, 256, 0, stream>>>(src, dst, Gin, row_start, sorted_u16, N, gs, E);

  const int ggrid = (N + 63) / 64;
  const int agrid = (N + 3) / 4;

  // 5. layer 1: h1 = bf16((x*so) @ W1)
  gemm1_kernel<<<ggrid, 256, 0, stream>>>(x, so, W1, h1, N);

  // 6. fused agg + layer-2 GEMM: h2 = bf16(relu(segsum(h1)*si+b1)*so @ W2)
  agg_gemm2_kernel<<<agrid, 256, 0, stream>>>(h1, row_start, sorted_u16, si, so,
                                              b1, W2, h2, N);

  // 7. out = segsum(h2)*si + b2
  agg_final_kernel<<<agrid, 256, 0, stream>>>(h2, row_start, sorted_u16, si, b2, out, N);
}

// Round 7
// 280.331 us; speedup vs baseline: 1.1328x; 1.1328x over previous
//
#include <hip/hip_runtime.h>

#define NF 64        // feature width
#define BC 32        // edge chunks
#define RANGE 8192   // node-range for LDS histograms (32 KB int counters)

// f32 -> bf16 round-to-nearest-even
__device__ __forceinline__ unsigned short f2bf(float f) {
  unsigned int u = __float_as_uint(f);
  return (unsigned short)((u + 0x7fffu + ((u >> 16) & 1u)) >> 16);
}

// ---------------------------------------------------------------------------
// Per-(range,chunk) LDS histograms (r5 structure: 448 small blocks, proven
// fast; r6's big-LDS few-blocks variant was latency-bound at 1.4% occupancy).
// kind 0: dst -> Gin[b][node] ; kind 1: src -> Gout[b][node] (ushort counts).
__global__ __launch_bounds__(256) void hist_kernel(
    const int* __restrict__ src, const int* __restrict__ dst,
    unsigned short* __restrict__ Gout, unsigned short* __restrict__ Gin,
    int n, int nE, int R) {
  __shared__ int cnt[RANGE];
  const int rb = blockIdx.x % (R * BC);
  const int kind = blockIdx.x / (R * BC);
  const int r = rb / BC, b = rb % BC;
  const int r0 = r * RANGE;
  for (int i = threadIdx.x; i < RANGE; i += 256) cnt[i] = 0;
  __syncthreads();
  const int* keys = kind ? src : dst;
  const int chunk = (nE + BC - 1) / BC;
  const int lo = b * chunk, hi = min(lo + chunk, nE);
  for (int e = lo + threadIdx.x; e < hi; e += 256) {
    unsigned int k = (unsigned int)(keys[e] - r0);
    if (k < (unsigned int)RANGE) atomicAdd(&cnt[k], 1);
  }
  __syncthreads();
  unsigned short* G = kind ? Gout : Gin;
  for (int i = threadIdx.x; i < RANGE; i += 256) {
    int nidx = r0 + i;
    if (nidx < n) G[(size_t)b * n + nidx] = (unsigned short)cnt[i];
  }
}

// ---------------------------------------------------------------------------
// Fused colscan + scan1 (identical thread-per-node shape): per node, exclusive
// scan of Gin down the chunks (in place -> per-chunk base) giving deg_in;
// sum Gout -> deg_out; then block-scan deg_in -> lscan + bsum.
__global__ __launch_bounds__(256) void colscan_scan1_kernel(
    unsigned short* __restrict__ Gin, const unsigned short* __restrict__ Gout,
    int* __restrict__ deg_in, int* __restrict__ deg_out,
    int* __restrict__ lscan, int* __restrict__ bsum, int n) {
  __shared__ int s[256];
  const int tid = threadIdx.x;
  const int i = blockIdx.x * 256 + tid;
  int di = 0;
  if (i < n) {
    int base = 0;
    #pragma unroll 8
    for (int b = 0; b < BC; ++b) {
      int c = Gin[(size_t)b * n + i];
      Gin[(size_t)b * n + i] = (unsigned short)base;
      base += c;
    }
    di = base;
    int dsum = 0;
    #pragma unroll 8
    for (int b = 0; b < BC; ++b) dsum += Gout[(size_t)b * n + i];
    deg_in[i] = di;
    deg_out[i] = dsum;
  }
  s[tid] = di;
  __syncthreads();
  #pragma unroll
  for (int off = 1; off < 256; off <<= 1) {
    int t2 = (tid >= off) ? s[tid - off] : 0;
    __syncthreads();
    s[tid] += t2;
    __syncthreads();
  }
  if (i < n) lscan[i] = s[tid] - di;
  if (tid == 255) bsum[blockIdx.x] = s[255];
}

// scan3: block b reduces bsum[0..b) itself (NB<=256), finalizes row_start and
// deg^{-1/2} factors.
__global__ __launch_bounds__(256) void scan3_kernel(
    const int* __restrict__ lscan, const int* __restrict__ bsum,
    const int* __restrict__ deg_out, const int* __restrict__ deg_in,
    int* __restrict__ row_start, float* __restrict__ so, float* __restrict__ si,
    int n, int nE) {
  __shared__ int red[256];
  const int tid = threadIdx.x;
  const int b = blockIdx.x;
  red[tid] = (tid < b) ? bsum[tid] : 0;
  __syncthreads();
  #pragma unroll
  for (int s = 128; s > 0; s >>= 1) {
    if (tid < s) red[tid] += red[tid + s];
    __syncthreads();
  }
  const int off = red[0];
  const int i = b * 256 + tid;
  if (b == 0 && tid == 0) row_start[n] = nE;
  if (i < n) {
    row_start[i] = lscan[i] + off;
    int dO = deg_out[i];
    int dI = deg_in[i];
    so[i] = dO > 0 ? rsqrtf((float)dO) : 0.f;
    si[i] = dI > 0 ? rsqrtf((float)dI) : 0.f;
  }
}

// Atomic-free placement, STANDALONE (r5 fused it under the GEMM's 236-VGPR
// occupancy cap -> 100 us; alone it runs ~5 blocks/CU). Block (r,b) rebuilds
// chunk-b local ranks for range r in LDS; pos = row_start[d]+Gin[b][d]+rank.
__global__ __launch_bounds__(256) void place_kernel(
    const int* __restrict__ src, const int* __restrict__ dst,
    const unsigned short* __restrict__ Gin, const int* __restrict__ row_start,
    unsigned short* __restrict__ sorted, int n, int nE) {
  __shared__ int cnt[RANGE];
  const int rb = blockIdx.x;
  const int r = rb / BC, b = rb % BC;
  const int r0 = r * RANGE;
  for (int i = threadIdx.x; i < RANGE; i += 256) cnt[i] = 0;
  __syncthreads();
  const int chunk = (nE + BC - 1) / BC;
  const int lo = b * chunk, hi = min(lo + chunk, nE);
  for (int e = lo + threadIdx.x; e < hi; e += 256) {
    int d = dst[e];
    unsigned int k = (unsigned int)(d - r0);
    if (k < (unsigned int)RANGE) {
      int rank = atomicAdd(&cnt[k], 1);
      int pos = row_start[d] + (int)Gin[(size_t)b * n + d] + rank;
      sorted[pos] = (unsigned short)src[e];
    }
  }
}

// ---------------------------------------------------------------------------
// Register-blocked GEMM (layer 1): h1 = bf16((x*so) @ W1).
__global__ __launch_bounds__(256) void gemm1_kernel(
    const float* __restrict__ A, const float* __restrict__ so,
    const float* __restrict__ W, unsigned short* __restrict__ H, int n) {
  __shared__ float Wl[NF * NF];
  __shared__ float Xl[NF * 68];
  const int t = threadIdx.x;

  #pragma unroll
  for (int i = 0; i < 16; ++i) Wl[t + 256 * i] = W[t + 256 * i];

  const int row0 = blockIdx.x * 64;
  #pragma unroll
  for (int i = 0; i < 16; ++i) {
    int idx = t + 256 * i;
    int r = idx >> 6;
    int c = idx & 63;
    int gr = row0 + r;
    float v = 0.f;
    if (gr < n) v = A[(size_t)gr * NF + c] * so[gr];
    Xl[r * 68 + c] = v;
  }
  __syncthreads();

  const int tx = t & 15;
  const int ty = t >> 4;
  float4 acc0 = {0, 0, 0, 0}, acc1 = {0, 0, 0, 0};
  float4 acc2 = {0, 0, 0, 0}, acc3 = {0, 0, 0, 0};

  #pragma unroll
  for (int k4 = 0; k4 < 16; ++k4) {
    const float4 a0 = *(const float4*)&Xl[(ty * 4 + 0) * 68 + k4 * 4];
    const float4 a1 = *(const float4*)&Xl[(ty * 4 + 1) * 68 + k4 * 4];
    const float4 a2 = *(const float4*)&Xl[(ty * 4 + 2) * 68 + k4 * 4];
    const float4 a3 = *(const float4*)&Xl[(ty * 4 + 3) * 68 + k4 * 4];
    const float4 b0 = *(const float4*)&Wl[(k4 * 4 + 0) * NF + tx * 4];
    const float4 b1 = *(const float4*)&Wl[(k4 * 4 + 1) * NF + tx * 4];
    const float4 b2 = *(const float4*)&Wl[(k4 * 4 + 2) * NF + tx * 4];
    const float4 b3 = *(const float4*)&Wl[(k4 * 4 + 3) * NF + tx * 4];

#define FMA4(ACC, AV, BV)                         \
    ACC.x = fmaf(AV, BV.x, ACC.x);                \
    ACC.y = fmaf(AV, BV.y, ACC.y);                \
    ACC.z = fmaf(AV, BV.z, ACC.z);                \
    ACC.w = fmaf(AV, BV.w, ACC.w);
    FMA4(acc0, a0.x, b0) FMA4(acc0, a0.y, b1) FMA4(acc0, a0.z, b2) FMA4(acc0, a0.w, b3)
    FMA4(acc1, a1.x, b0) FMA4(acc1, a1.y, b1) FMA4(acc1, a1.z, b2) FMA4(acc1, a1.w, b3)
    FMA4(acc2, a2.x, b0) FMA4(acc2, a2.y, b1) FMA4(acc2, a2.z, b2) FMA4(acc2, a2.w, b3)
    FMA4(acc3, a3.x, b0) FMA4(acc3, a3.y, b1) FMA4(acc3, a3.z, b2) FMA4(acc3, a3.w, b3)
#undef FMA4
  }

  const int col = tx * 4;
  #pragma unroll
  for (int i = 0; i < 4; ++i) {
    int gr = row0 + ty * 4 + i;
    if (gr >= n) continue;
    float4 v = (i == 0) ? acc0 : (i == 1) ? acc1 : (i == 2) ? acc2 : acc3;
    ushort4 o;
    o.x = f2bf(v.x); o.y = f2bf(v.y); o.z = f2bf(v.z); o.w = f2bf(v.w);
    *(ushort4*)&H[(size_t)gr * NF + col] = o;
  }
}

// ---------------------------------------------------------------------------
// Shared gather/accumulate: one wave per node over bf16 rows (128 B). Lane
// group g=lane>>3 handles row srcs[e+g]; lane loads float4 = 8 bf16 -> one
// instruction gathers 8 rows. Butterfly xor 8/16/32 leaves the FULL row sum
// in every lane (features (lane&7)*8 .. +7 in acc[0..7]).
__device__ __forceinline__ void gather_sum(
    const unsigned short* __restrict__ H, const unsigned short* __restrict__ srcs,
    int beg, int end, int g, int c, float* acc) {
  const float4* Hv = (const float4*)H;
  int e = beg;
  for (; e + 16 <= end; e += 16) {
    int ia = srcs[e + g];
    int ib = srcs[e + 8 + g];
    float4 va = Hv[(size_t)ia * 8 + c];
    float4 vb = Hv[(size_t)ib * 8 + c];
    const unsigned int* pa = (const unsigned int*)&va;
    const unsigned int* pb = (const unsigned int*)&vb;
    #pragma unroll
    for (int k = 0; k < 4; ++k) {
      acc[2 * k]     += __uint_as_float(pa[k] << 16) + __uint_as_float(pb[k] << 16);
      acc[2 * k + 1] += __uint_as_float(pa[k] & 0xffff0000u) + __uint_as_float(pb[k] & 0xffff0000u);
    }
  }
  if (e + 8 <= end) {
    int ia = srcs[e + g];
    float4 va = Hv[(size_t)ia * 8 + c];
    const unsigned int* pa = (const unsigned int*)&va;
    #pragma unroll
    for (int k = 0; k < 4; ++k) {
      acc[2 * k]     += __uint_as_float(pa[k] << 16);
      acc[2 * k + 1] += __uint_as_float(pa[k] & 0xffff0000u);
    }
    e += 8;
  }
  if (e < end) {
    int idx = (e + g < end) ? (e + g) : (end - 1);
    float m = (e + g < end) ? 1.f : 0.f;
    int ia = srcs[idx];
    float4 va = Hv[(size_t)ia * 8 + c];
    const unsigned int* pa = (const unsigned int*)&va;
    #pragma unroll
    for (int k = 0; k < 4; ++k) {
      acc[2 * k]     += m * __uint_as_float(pa[k] << 16);
      acc[2 * k + 1] += m * __uint_as_float(pa[k] & 0xffff0000u);
    }
  }
  #pragma unroll
  for (int d = 8; d <= 32; d <<= 1) {
    #pragma unroll
    for (int k = 0; k < 8; ++k) acc[k] += __shfl_xor(acc[k], d);
  }
}

// Fused agg0 + layer-2 GEMM: t = relu(segsum(h1)*si + b1) * so in-register,
// then per-node matvec h2[node][j] = sum_k t[k]*W2[k][j] via shfl + LDS W2.
__global__ __launch_bounds__(256) void agg_gemm2_kernel(
    const unsigned short* __restrict__ H1, const int* __restrict__ row_start,
    const unsigned short* __restrict__ srcs, const float* __restrict__ si,
    const float* __restrict__ so, const float* __restrict__ b1,
    const float* __restrict__ W2, unsigned short* __restrict__ H2, int n) {
  __shared__ float Wl[NF * NF];
  const int t = threadIdx.x;
  #pragma unroll
  for (int i = 0; i < 16; ++i) Wl[t + 256 * i] = W2[t + 256 * i];
  __syncthreads();

  int node = blockIdx.x * 4 + (t >> 6);
  if (node >= n) return;
  const int lane = t & 63;
  const int g = lane >> 3;
  const int c = lane & 7;

  float acc[8] = {0, 0, 0, 0, 0, 0, 0, 0};
  gather_sum(H1, srcs, row_start[node], row_start[node + 1], g, c, acc);

  const float sin = si[node];
  const float son = so[node];
  #pragma unroll
  for (int k = 0; k < 8; ++k)
    acc[k] = fmaxf(fmaf(acc[k], sin, b1[c * 8 + k]), 0.f) * son;

  float o = 0.f;
  #pragma unroll
  for (int k = 0; k < NF; ++k) {
    float tk = __shfl(acc[k & 7], k >> 3);
    o = fmaf(tk, Wl[k * NF + lane], o);
  }
  H2[(size_t)node * NF + lane] = f2bf(o);
}

// Final aggregation: out = segsum(h2)*si + b2 (f32 output).
__global__ __launch_bounds__(256) void agg_final_kernel(
    const unsigned short* __restrict__ H2, const int* __restrict__ row_start,
    const unsigned short* __restrict__ srcs, const float* __restrict__ si,
    const float* __restrict__ b2, float* __restrict__ out, int n) {
  int node = blockIdx.x * 4 + (threadIdx.x >> 6);
  if (node >= n) return;
  const int lane = threadIdx.x & 63;
  const int g = lane >> 3;
  const int c = lane & 7;

  float acc[8] = {0, 0, 0, 0, 0, 0, 0, 0};
  gather_sum(H2, srcs, row_start[node], row_start[node + 1], g, c, acc);

  if (g == 0) {
    const float sin = si[node];
    const float4 b4a = *(const float4*)&b2[c * 8];
    const float4 b4b = *(const float4*)&b2[c * 8 + 4];
    const float bb[8] = {b4a.x, b4a.y, b4a.z, b4a.w, b4b.x, b4b.y, b4b.z, b4b.w};
    float r[8];
    #pragma unroll
    for (int k = 0; k < 8; ++k) r[k] = fmaf(acc[k], sin, bb[k]);
    *(float4*)&out[(size_t)node * NF + c * 8]     = make_float4(r[0], r[1], r[2], r[3]);
    *(float4*)&out[(size_t)node * NF + c * 8 + 4] = make_float4(r[4], r[5], r[6], r[7]);
  }
}

// ---------------------------------------------------------------------------
extern "C" void kernel_launch(void* const* d_in, const int* in_sizes, int n_in,
                              void* d_out, int out_size, void* d_ws, size_t ws_size,
                              hipStream_t stream) {
  const float* x  = (const float*)d_in[0];
  const float* W1 = (const float*)d_in[1];
  const float* b1 = (const float*)d_in[2];
  const float* W2 = (const float*)d_in[3];
  const float* b2 = (const float*)d_in[4];
  const int* src  = (const int*)d_in[5];
  const int* dst  = (const int*)d_in[6];
  float* out = (float*)d_out;

  const int N = in_sizes[0] / NF;   // 50000 (< 65536 for ushort ids)
  const int E = in_sizes[5];        // 800000
  const int NB = (N + 255) / 256;   // 196 <= 256
  const int R  = (N + RANGE - 1) / RANGE;  // 7 ranges

  // Workspace (~23 MB), no memsets needed.
  char* ws = (char*)d_ws;
  size_t p = 0;
  auto alloc = [&](size_t bytes) -> void* {
    void* r = ws + p;
    p = (p + bytes + 255) & ~(size_t)255;
    return r;
  };
  int*   deg_out_i  = (int*)  alloc((size_t)N * 4);
  int*   deg_in_i   = (int*)  alloc((size_t)N * 4);
  float* so         = (float*)alloc((size_t)N * 4);
  float* si         = (float*)alloc((size_t)N * 4);
  int*   row_start  = (int*)  alloc((size_t)(N + 1) * 4);
  int*   bsum       = (int*)  alloc((size_t)NB * 4);
  int*   lscan      = (int*)  alloc((size_t)N * 4);
  unsigned short* sorted_u16 = (unsigned short*)alloc((size_t)E * 2);
  unsigned short* h1   = (unsigned short*)alloc((size_t)N * NF * 2);  // bf16
  unsigned short* h2   = (unsigned short*)alloc((size_t)N * NF * 2);  // bf16
  unsigned short* G_in  = (unsigned short*)alloc((size_t)BC * N * 2); // 3.2 MB
  unsigned short* G_out = (unsigned short*)alloc((size_t)BC * N * 2); // 3.2 MB

  // 1. per-(range,chunk) histograms for both endpoints
  hist_kernel<<<2 * R * BC, 256, 0, stream>>>(src, dst, G_out, G_in, N, E, R);

  // 2. fused column-scan (per-chunk bases + degrees) + block scan
  colscan_scan1_kernel<<<NB, 256, 0, stream>>>(G_in, G_out, deg_in_i, deg_out_i,
                                               lscan, bsum, N);

  // 3. row_start + so/si
  scan3_kernel<<<NB, 256, 0, stream>>>(lscan, bsum, deg_out_i, deg_in_i,
                                       row_start, so, si, N, E);

  // 4. atomic-free placement (standalone: full occupancy)
  place_kernel<<<R * BC, 256, 0, stream>>>(src, dst, G_in, row_start,
                                           sorted_u16, N, E);

  const int ggrid = (N + 63) / 64;
  const int agrid = (N + 3) / 4;

  // 5. layer 1: h1 = bf16((x*so) @ W1)
  gemm1_kernel<<<ggrid, 256, 0, stream>>>(x, so, W1, h1, N);

  // 6. fused agg + layer-2 GEMM: h2 = bf16(relu(segsum(h1)*si+b1)*so @ W2)
  agg_gemm2_kernel<<<agrid, 256, 0, stream>>>(h1, row_start, sorted_u16, si, so,
                                              b1, W2, h2, N);

  // 7. out = segsum(h2)*si + b2
  agg_final_kernel<<<agrid, 256, 0, stream>>>(h2, row_start, sorted_u16, si, b2, out, N);
}